// Round 9
// baseline (146.911 us; speedup 1.0000x reference)
//
#include <hip/hip_runtime.h>

#define NPTS 65536
#define NU_F 0.0031830988618379067f

typedef __attribute__((ext_vector_type(8))) _Float16 half8v;  // 8 fp16 (4 VGPRs)
typedef __attribute__((ext_vector_type(4))) float    f32x4;   // 16x16 MFMA C/D

// 5-stream tanh jet: value, d/dt, d/dx, d/dy, laplacian (uxx+uyy merged — linear
// through W; tanh update needs only zx, zy individually, which streams 2,3 carry).
__device__ __forceinline__ void jet5(float z, float zt, float zx, float zy, float zl,
                                     float& s0, float& s1, float& s2, float& s3, float& s4) {
    float e  = __expf(2.0f * z);
    float a  = 1.0f - 2.0f * __builtin_amdgcn_rcpf(e + 1.0f);
    float ap = 1.0f - a * a;
    float am = -2.0f * a * ap;
    s0 = a;
    s1 = ap * zt;
    s2 = ap * zx;
    s3 = ap * zy;
    s4 = ap * zl + am * (zx * zx + zy * zy);
}

// ---- jet LDS: row sp = stream*16 + point (512 B/row), slot bits [8:4] ^= sp&31 ----
__device__ __forceinline__ int swzoff(int sp, int byteInRow) {
    return (sp << 9) + (byteInRow ^ ((sp & 31) << 4));
}
union h4u { ushort4 u4; _Float16 h[4]; };
__device__ __forceinline__ void storeJ(char* baseB, int sp, int j0,
                                       _Float16 a0, _Float16 a1, _Float16 a2, _Float16 a3) {
    h4u v; v.h[0] = a0; v.h[1] = a1; v.h[2] = a2; v.h[3] = a3;
    *(ushort4*)(baseB + swzoff(sp, j0 * 2)) = v.u4;
}

// ============ prep: W1..W3 -> fp16 in 16x16x32 A-fragment order (HW-verified R2) ============
// A-frag: lane 16g+r holds A[row r][k = 8g+jj], jj=0..7. A = W^T (row=j, k=input).
// Frag idx = (M*8 + kt)*64 + lane, M = j/16, kt = k/32.
__global__ __launch_bounds__(256)
void pinn_prep_kernel(const float* __restrict__ W1, const float* __restrict__ W2,
                      const float* __restrict__ W3, _Float16* __restrict__ ws) {
    int gid  = blockIdx.x * 256 + threadIdx.x;  // 0..24575
    int l    = gid >> 13;                       // layer 0..2
    int rem  = gid & 8191;
    int M    = rem >> 9;                        // 0..15
    int kt   = (rem >> 6) & 7;                  // 0..7
    int lane = rem & 63;
    const float* W = (l == 0) ? W1 : (l == 1) ? W2 : W3;
    int j  = M * 16 + (lane & 15);
    int k0 = kt * 32 + (lane >> 4) * 8;
    union { _Float16 h[8]; half8v v; } hf;
    #pragma unroll
    for (int jj = 0; jj < 8; ++jj)
        hf.h[jj] = (_Float16)W[(k0 + jj) * 256 + j];   // W[k][j] row-major
    ((half8v*)ws)[l * 8192 + (M * 8 + kt) * 64 + lane] = hf.v;
}

// ============== main: 16 points / block, 256 threads, 4 waves, 16x16x32 f16 ==============
// Wave wv owns j in [wv*64, wv*64+64) = M-tiles {4wv..4wv+3}. B col-tile c = stream c
// (16 cols = 16 points). C layout: col=lane&15=point; row=(lane>>4)*4 + reg i.
// All 5 streams of a (point,j) are lane-local -> no cross-lane exchange.
// launch_bounds(256,4): VGPR budget 128 (demand ~120); LDS 40 KiB -> 4 blocks/CU.
__global__ __launch_bounds__(256, 4)
void pinn_burger2d_kernel(
    const float* __restrict__ t, const float* __restrict__ x, const float* __restrict__ y,
    const float* __restrict__ W0, const float* __restrict__ b0,
    const float* __restrict__ b1, const float* __restrict__ b2, const float* __restrict__ b3,
    const float* __restrict__ W4, const float* __restrict__ b4,
    const _Float16* __restrict__ wf, float* __restrict__ out)
{
    __shared__ _Float16 BjS[5 * 16 * 256];   // 40 KiB: rows sp = s*16 + p
    char* bjB = (char*)BjS;

    const int tid  = threadIdx.x;
    const int lane = tid & 63;
    const int wv   = tid >> 6;          // wave 0..3
    const int p    = lane & 15;         // point 0..15 (MFMA B/C column)
    const int quad = lane >> 4;         // 0..3 (k-group on read, row-group on C)
    const int base = blockIdx.x * 16;
    const int gi   = base + p;

    const float tv = t[gi], xv = x[gi], yv = y[gi];

    // ---------------- layer 0: (t,x,y) -> 256-wide 5-stream jet, to LDS ----------------
    #pragma unroll
    for (int m = 0; m < 4; ++m) {
        const int j0 = wv * 64 + m * 16 + quad * 4;
        float4 w0t = *(const float4*)(W0 + j0);
        float4 w0x = *(const float4*)(W0 + 256 + j0);
        float4 w0y = *(const float4*)(W0 + 512 + j0);
        float4 bb  = *(const float4*)(b0 + j0);
        float wtA[4] = {w0t.x, w0t.y, w0t.z, w0t.w};
        float wxA[4] = {w0x.x, w0x.y, w0x.z, w0x.w};
        float wyA[4] = {w0y.x, w0y.y, w0y.z, w0y.w};
        float bbA[4] = {bb.x, bb.y, bb.z, bb.w};
        _Float16 h[5][4];
        #pragma unroll
        for (int i = 0; i < 4; ++i) {
            float z = tv * wtA[i] + xv * wxA[i] + yv * wyA[i] + bbA[i];
            float s0, s1, s2, s3, s4;
            jet5(z, wtA[i], wxA[i], wyA[i], 0.0f, s0, s1, s2, s3, s4);
            h[0][i] = (_Float16)s0; h[1][i] = (_Float16)s1; h[2][i] = (_Float16)s2;
            h[3][i] = (_Float16)s3; h[4][i] = (_Float16)s4;
        }
        #pragma unroll
        for (int s = 0; s < 5; ++s)
            storeJ(bjB, s * 16 + p, j0, h[s][0], h[s][1], h[s][2], h[s][3]);
    }
    __syncthreads();

    f32x4 acc[4][5];   // [M-tile m][stream c]

    for (int li = 0; li < 3; ++li) {
        #pragma unroll
        for (int m = 0; m < 4; ++m)
            #pragma unroll
            for (int c = 0; c < 5; ++c)
                acc[m][c] = (f32x4)(0.0f);

        const half8v* whf = (const half8v*)wf + li * 8192;

        #pragma unroll 2
        for (int kt = 0; kt < 8; ++kt) {
            const int bRow = kt * 64 + quad * 16;    // 8 consecutive k (16 B) per lane
            half8v bv0 = *(const half8v*)(bjB + swzoff(     p, bRow));
            half8v bv1 = *(const half8v*)(bjB + swzoff(16 + p, bRow));
            half8v bv2 = *(const half8v*)(bjB + swzoff(32 + p, bRow));
            half8v bv3 = *(const half8v*)(bjB + swzoff(48 + p, bRow));
            half8v bv4 = *(const half8v*)(bjB + swzoff(64 + p, bRow));
            #pragma unroll
            for (int m = 0; m < 4; ++m) {
                half8v wh = whf[((wv * 4 + m) * 8 + kt) * 64 + lane];
                acc[m][0] = __builtin_amdgcn_mfma_f32_16x16x32_f16(wh, bv0, acc[m][0], 0, 0, 0);
                acc[m][1] = __builtin_amdgcn_mfma_f32_16x16x32_f16(wh, bv1, acc[m][1], 0, 0, 0);
                acc[m][2] = __builtin_amdgcn_mfma_f32_16x16x32_f16(wh, bv2, acc[m][2], 0, 0, 0);
                acc[m][3] = __builtin_amdgcn_mfma_f32_16x16x32_f16(wh, bv3, acc[m][3], 0, 0, 0);
                acc[m][4] = __builtin_amdgcn_mfma_f32_16x16x32_f16(wh, bv4, acc[m][4], 0, 0, 0);
            }
        }
        __syncthreads();   // all waves done reading jet LDS

        if (li < 2) {
            // ---- lane-local tanh jet + store next jet (no shuffles) ----
            const float* bL = (li == 0) ? b1 : b2;
            #pragma unroll
            for (int m = 0; m < 4; ++m) {
                const int j0 = (wv * 4 + m) * 16 + quad * 4;   // rows for regs 0..3
                float4 bb = *(const float4*)(bL + j0);
                float bbA[4] = {bb.x, bb.y, bb.z, bb.w};
                _Float16 h[5][4];
                #pragma unroll
                for (int i = 0; i < 4; ++i) {
                    float s0, s1, s2, s3, s4;
                    jet5(acc[m][0][i] + bbA[i], acc[m][1][i], acc[m][2][i],
                         acc[m][3][i], acc[m][4][i], s0, s1, s2, s3, s4);
                    h[0][i] = (_Float16)s0; h[1][i] = (_Float16)s1; h[2][i] = (_Float16)s2;
                    h[3][i] = (_Float16)s3; h[4][i] = (_Float16)s4;
                }
                #pragma unroll
                for (int s = 0; s < 5; ++s)
                    storeJ(bjB, s * 16 + p, j0, h[s][0], h[s][1], h[s][2], h[s][3]);
            }
            __syncthreads();
        }
    }

    // ---------------- layer-3 jet (lane-local) + final 256->1 dot ----------------
    float part[5] = {0, 0, 0, 0, 0};
    #pragma unroll
    for (int m = 0; m < 4; ++m) {
        const int j0 = (wv * 4 + m) * 16 + quad * 4;
        float4 bb = *(const float4*)(b3 + j0);
        float4 w4 = *(const float4*)(W4 + j0);
        float bbA[4] = {bb.x, bb.y, bb.z, bb.w};
        float w4A[4] = {w4.x, w4.y, w4.z, w4.w};
        #pragma unroll
        for (int i = 0; i < 4; ++i) {
            float s0, s1, s2, s3, s4;
            jet5(acc[m][0][i] + bbA[i], acc[m][1][i], acc[m][2][i],
                 acc[m][3][i], acc[m][4][i], s0, s1, s2, s3, s4);
            part[0] += s0 * w4A[i];
            part[1] += s1 * w4A[i];
            part[2] += s2 * w4A[i];
            part[3] += s3 * w4A[i];
            part[4] += s4 * w4A[i];
        }
    }
    // lanes p, p+16, p+32, p+48 share a point (4 row-groups)
    #pragma unroll
    for (int s = 0; s < 5; ++s) {
        part[s] += __shfl_xor(part[s], 16, 64);
        part[s] += __shfl_xor(part[s], 32, 64);
    }

    float* resf = (float*)BjS;   // overlay; sync after last kt loop protects
    if (lane < 16) {
        #pragma unroll
        for (int s = 0; s < 5; ++s) resf[(wv * 5 + s) * 16 + p] = part[s];
    }
    __syncthreads();

    if (tid < 16) {
        const int pp = tid;
        const int g  = base + pp;
        float u = b4[0], ut = 0, ux = 0, uy = 0, lap = 0;
        #pragma unroll
        for (int w = 0; w < 4; ++w) {
            u   += resf[(w * 5 + 0) * 16 + pp];
            ut  += resf[(w * 5 + 1) * 16 + pp];
            ux  += resf[(w * 5 + 2) * 16 + pp];
            uy  += resf[(w * 5 + 3) * 16 + pp];
            lap += resf[(w * 5 + 4) * 16 + pp];
        }
        out[g]        = u;
        out[NPTS + g] = ut + u * ux + u * uy - NU_F * lap;
    }
}

extern "C" void kernel_launch(void* const* d_in, const int* in_sizes, int n_in,
                              void* d_out, int out_size, void* d_ws, size_t ws_size,
                              hipStream_t stream) {
    const float* t  = (const float*)d_in[0];
    const float* x  = (const float*)d_in[1];
    const float* y  = (const float*)d_in[2];
    const float* W0 = (const float*)d_in[3];
    const float* b0 = (const float*)d_in[4];
    const float* W1 = (const float*)d_in[5];
    const float* b1 = (const float*)d_in[6];
    const float* W2 = (const float*)d_in[7];
    const float* b2 = (const float*)d_in[8];
    const float* W3 = (const float*)d_in[9];
    const float* b3 = (const float*)d_in[10];
    const float* W4 = (const float*)d_in[11];
    const float* b4 = (const float*)d_in[12];
    float* out = (float*)d_out;

    pinn_prep_kernel<<<96, 256, 0, stream>>>(W1, W2, W3, (_Float16*)d_ws);
    pinn_burger2d_kernel<<<NPTS / 16, 256, 0, stream>>>(
        t, x, y, W0, b0, b1, b2, b3, W4, b4, (const _Float16*)d_ws, out);
}

// Round 11
// 143.035 us; speedup vs baseline: 1.0271x; 1.0271x over previous
//
#include <hip/hip_runtime.h>

#define NPTS 65536
#define NU_F 0.0031830988618379067f

typedef __attribute__((ext_vector_type(8))) _Float16 half8v;  // 8 fp16 (4 VGPRs)
typedef __attribute__((ext_vector_type(2))) __fp16   fp16x2;  // cvt_pkrtz result type
typedef __attribute__((ext_vector_type(4))) float    f32x4;   // 16x16 MFMA C/D

__device__ __forceinline__ unsigned pk2(float a, float b) {
    union { fp16x2 h; unsigned u; } c;
    c.h = __builtin_amdgcn_cvt_pkrtz(a, b);   // v_cvt_pkrtz_f16_f32: 1 inst, 2 converts
    return c.u;
}

// 5-stream tanh jet: value, d/dt, d/dx, d/dy, laplacian (uxx+uyy merged — linear
// through W; tanh update needs only zx, zy individually, which streams 2,3 carry).
__device__ __forceinline__ void jet5(float z, float zt, float zx, float zy, float zl,
                                     float& s0, float& s1, float& s2, float& s3, float& s4) {
    float e  = __expf(2.0f * z);
    float a  = 1.0f - 2.0f * __builtin_amdgcn_rcpf(e + 1.0f);
    float ap = 1.0f - a * a;
    s0 = a;
    s1 = ap * zt;
    s2 = ap * zx;
    s3 = ap * zy;
    // s4 = ap*zl + am*(zx^2+zy^2), am = -2a*ap  ->  ap*(zl - 2a*(zx^2+zy^2))
    float q = zx * zx + zy * zy;
    s4 = ap * __builtin_fmaf(-2.0f * a, q, zl);
}

// ---- jet LDS: row sp = stream*16 + point (512 B/row), slot bits [8:4] ^= sp&31 ----
__device__ __forceinline__ int swzoff(int sp, int byteInRow) {
    return (sp << 9) + (byteInRow ^ ((sp & 31) << 4));
}
__device__ __forceinline__ void storeJ2(char* baseB, int sp, int j0,
                                        unsigned lo, unsigned hi) {
    *(uint2*)(baseB + swzoff(sp, j0 * 2)) = make_uint2(lo, hi);
}

// ============ prep: W1..W3 -> fp16 in 16x16x32 A-fragment order (HW-verified R2) ============
// A-frag: lane 16g+r holds A[row r][k = 8g+jj], jj=0..7. A = W^T (row=j, k=input).
// Frag idx = (M*8 + kt)*64 + lane, M = j/16, kt = k/32.
__global__ __launch_bounds__(256)
void pinn_prep_kernel(const float* __restrict__ W1, const float* __restrict__ W2,
                      const float* __restrict__ W3, _Float16* __restrict__ ws) {
    int gid  = blockIdx.x * 256 + threadIdx.x;  // 0..24575
    int l    = gid >> 13;                       // layer 0..2
    int rem  = gid & 8191;
    int M    = rem >> 9;                        // 0..15
    int kt   = (rem >> 6) & 7;                  // 0..7
    int lane = rem & 63;
    const float* W = (l == 0) ? W1 : (l == 1) ? W2 : W3;
    int j  = M * 16 + (lane & 15);
    int k0 = kt * 32 + (lane >> 4) * 8;
    union { _Float16 h[8]; half8v v; } hf;
    #pragma unroll
    for (int jj = 0; jj < 8; ++jj)
        hf.h[jj] = (_Float16)W[(k0 + jj) * 256 + j];   // W[k][j] row-major (RNE)
    ((half8v*)ws)[l * 8192 + (M * 8 + kt) * 64 + lane] = hf.v;
}

// ============== main: 16 points / block, 256 threads, 4 waves, 16x16x32 f16 ==============
// Wave wv owns j in [wv*64, wv*64+64) = M-tiles {4wv..4wv+3}. B col-tile c = stream c
// (16 cols = 16 points). C layout: col=lane&15=point; row=(lane>>4)*4 + reg i.
// All 5 streams of a (point,j) are lane-local -> no cross-lane exchange.
// launch_bounds(256,3): budget 170 with slack (R9 lesson: a tight budget (128) made the
// allocator fall to 64 regs + heavy spill). Actual demand ~115 -> 4 waves/EU at runtime.
__global__ __launch_bounds__(256, 3)
void pinn_burger2d_kernel(
    const float* __restrict__ t, const float* __restrict__ x, const float* __restrict__ y,
    const float* __restrict__ W0, const float* __restrict__ b0,
    const float* __restrict__ b1, const float* __restrict__ b2, const float* __restrict__ b3,
    const float* __restrict__ W4, const float* __restrict__ b4,
    const _Float16* __restrict__ wf, float* __restrict__ out)
{
    __shared__ _Float16 BjS[5 * 16 * 256];   // 40 KiB: rows sp = s*16 + p
    char* bjB = (char*)BjS;

    const int tid  = threadIdx.x;
    const int lane = tid & 63;
    const int wv   = tid >> 6;          // wave 0..3
    const int p    = lane & 15;         // point 0..15 (MFMA B/C column)
    const int quad = lane >> 4;         // 0..3 (k-group on read, row-group on C)
    const int base = blockIdx.x * 16;
    const int gi   = base + p;

    const float tv = t[gi], xv = x[gi], yv = y[gi];

    // ---------------- layer 0: (t,x,y) -> 256-wide 5-stream jet, to LDS ----------------
    #pragma unroll
    for (int m = 0; m < 4; ++m) {
        const int j0 = wv * 64 + m * 16 + quad * 4;
        float4 w0t = *(const float4*)(W0 + j0);
        float4 w0x = *(const float4*)(W0 + 256 + j0);
        float4 w0y = *(const float4*)(W0 + 512 + j0);
        float4 bb  = *(const float4*)(b0 + j0);
        float wtA[4] = {w0t.x, w0t.y, w0t.z, w0t.w};
        float wxA[4] = {w0x.x, w0x.y, w0x.z, w0x.w};
        float wyA[4] = {w0y.x, w0y.y, w0y.z, w0y.w};
        float bbA[4] = {bb.x, bb.y, bb.z, bb.w};
        float ss[5][4];
        #pragma unroll
        for (int i = 0; i < 4; ++i) {
            float z = tv * wtA[i] + xv * wxA[i] + yv * wyA[i] + bbA[i];
            jet5(z, wtA[i], wxA[i], wyA[i], 0.0f,
                 ss[0][i], ss[1][i], ss[2][i], ss[3][i], ss[4][i]);
        }
        #pragma unroll
        for (int s = 0; s < 5; ++s)
            storeJ2(bjB, s * 16 + p, j0, pk2(ss[s][0], ss[s][1]), pk2(ss[s][2], ss[s][3]));
    }
    __syncthreads();

    f32x4 acc[4][5];   // [M-tile m][stream c]

    for (int li = 0; li < 3; ++li) {
        #pragma unroll
        for (int m = 0; m < 4; ++m)
            #pragma unroll
            for (int c = 0; c < 5; ++c)
                acc[m][c] = (f32x4)(0.0f);

        const half8v* whf = (const half8v*)wf + li * 8192;

        #pragma unroll 2
        for (int kt = 0; kt < 8; ++kt) {
            const int bRow = kt * 64 + quad * 16;    // 8 consecutive k (16 B) per lane
            half8v bv0 = *(const half8v*)(bjB + swzoff(     p, bRow));
            half8v bv1 = *(const half8v*)(bjB + swzoff(16 + p, bRow));
            half8v bv2 = *(const half8v*)(bjB + swzoff(32 + p, bRow));
            half8v bv3 = *(const half8v*)(bjB + swzoff(48 + p, bRow));
            half8v bv4 = *(const half8v*)(bjB + swzoff(64 + p, bRow));
            __builtin_amdgcn_s_setprio(1);
            #pragma unroll
            for (int m = 0; m < 4; ++m) {
                half8v wh = whf[((wv * 4 + m) * 8 + kt) * 64 + lane];
                acc[m][0] = __builtin_amdgcn_mfma_f32_16x16x32_f16(wh, bv0, acc[m][0], 0, 0, 0);
                acc[m][1] = __builtin_amdgcn_mfma_f32_16x16x32_f16(wh, bv1, acc[m][1], 0, 0, 0);
                acc[m][2] = __builtin_amdgcn_mfma_f32_16x16x32_f16(wh, bv2, acc[m][2], 0, 0, 0);
                acc[m][3] = __builtin_amdgcn_mfma_f32_16x16x32_f16(wh, bv3, acc[m][3], 0, 0, 0);
                acc[m][4] = __builtin_amdgcn_mfma_f32_16x16x32_f16(wh, bv4, acc[m][4], 0, 0, 0);
            }
            __builtin_amdgcn_s_setprio(0);
        }
        __syncthreads();   // all waves done reading jet LDS

        if (li < 2) {
            // ---- lane-local tanh jet + store next jet (no shuffles) ----
            const float* bL = (li == 0) ? b1 : b2;
            #pragma unroll
            for (int m = 0; m < 4; ++m) {
                const int j0 = (wv * 4 + m) * 16 + quad * 4;   // rows for regs 0..3
                float4 bb = *(const float4*)(bL + j0);
                float bbA[4] = {bb.x, bb.y, bb.z, bb.w};
                float ss[5][4];
                #pragma unroll
                for (int i = 0; i < 4; ++i) {
                    jet5(acc[m][0][i] + bbA[i], acc[m][1][i], acc[m][2][i],
                         acc[m][3][i], acc[m][4][i],
                         ss[0][i], ss[1][i], ss[2][i], ss[3][i], ss[4][i]);
                }
                #pragma unroll
                for (int s = 0; s < 5; ++s)
                    storeJ2(bjB, s * 16 + p, j0, pk2(ss[s][0], ss[s][1]), pk2(ss[s][2], ss[s][3]));
            }
            __syncthreads();
        }
    }

    // ---------------- layer-3 jet (lane-local) + final 256->1 dot ----------------
    float part[5] = {0, 0, 0, 0, 0};
    #pragma unroll
    for (int m = 0; m < 4; ++m) {
        const int j0 = (wv * 4 + m) * 16 + quad * 4;
        float4 bb = *(const float4*)(b3 + j0);
        float4 w4 = *(const float4*)(W4 + j0);
        float bbA[4] = {bb.x, bb.y, bb.z, bb.w};
        float w4A[4] = {w4.x, w4.y, w4.z, w4.w};
        #pragma unroll
        for (int i = 0; i < 4; ++i) {
            float s0, s1, s2, s3, s4;
            jet5(acc[m][0][i] + bbA[i], acc[m][1][i], acc[m][2][i],
                 acc[m][3][i], acc[m][4][i], s0, s1, s2, s3, s4);
            part[0] += s0 * w4A[i];
            part[1] += s1 * w4A[i];
            part[2] += s2 * w4A[i];
            part[3] += s3 * w4A[i];
            part[4] += s4 * w4A[i];
        }
    }
    // lanes p, p+16, p+32, p+48 share a point (4 row-groups)
    #pragma unroll
    for (int s = 0; s < 5; ++s) {
        part[s] += __shfl_xor(part[s], 16, 64);
        part[s] += __shfl_xor(part[s], 32, 64);
    }

    float* resf = (float*)BjS;   // overlay; sync after last kt loop protects
    if (lane < 16) {
        #pragma unroll
        for (int s = 0; s < 5; ++s) resf[(wv * 5 + s) * 16 + p] = part[s];
    }
    __syncthreads();

    if (tid < 16) {
        const int pp = tid;
        const int g  = base + pp;
        float u = b4[0], ut = 0, ux = 0, uy = 0, lap = 0;
        #pragma unroll
        for (int w = 0; w < 4; ++w) {
            u   += resf[(w * 5 + 0) * 16 + pp];
            ut  += resf[(w * 5 + 1) * 16 + pp];
            ux  += resf[(w * 5 + 2) * 16 + pp];
            uy  += resf[(w * 5 + 3) * 16 + pp];
            lap += resf[(w * 5 + 4) * 16 + pp];
        }
        out[g]        = u;
        out[NPTS + g] = ut + u * ux + u * uy - NU_F * lap;
    }
}

extern "C" void kernel_launch(void* const* d_in, const int* in_sizes, int n_in,
                              void* d_out, int out_size, void* d_ws, size_t ws_size,
                              hipStream_t stream) {
    const float* t  = (const float*)d_in[0];
    const float* x  = (const float*)d_in[1];
    const float* y  = (const float*)d_in[2];
    const float* W0 = (const float*)d_in[3];
    const float* b0 = (const float*)d_in[4];
    const float* W1 = (const float*)d_in[5];
    const float* b1 = (const float*)d_in[6];
    const float* W2 = (const float*)d_in[7];
    const float* b2 = (const float*)d_in[8];
    const float* W3 = (const float*)d_in[9];
    const float* b3 = (const float*)d_in[10];
    const float* W4 = (const float*)d_in[11];
    const float* b4 = (const float*)d_in[12];
    float* out = (float*)d_out;

    pinn_prep_kernel<<<96, 256, 0, stream>>>(W1, W2, W3, (_Float16*)d_ws);
    pinn_burger2d_kernel<<<NPTS / 16, 256, 0, stream>>>(
        t, x, y, W0, b0, b1, b2, b3, W4, b4, (const _Float16*)d_ws, out);
}